// Round 11
// baseline (2219.929 us; speedup 1.0000x reference)
//
#include <hip/hip_runtime.h>
#include <stdint.h>

#define NPTS   32768
#define NBATCH 8
#define NFPS   512
#define NGRP   32
#define BIGF   1e10f
#define R2F    0.04f
#define CAP    512
#define QPB    4      // ball-query centroids per block

// FPS decomposition
#define P      8                  // blocks per batch
#define PPB    (NPTS / P)         // 4096 points per block
#define CHUNKS (PPB / 4)          // 1024 float4-chunks per block
#define THR    512                // threads per fps block
#define CPT    (CHUNKS / THR)     // 2 chunks (8 points) per thread
#define NSLOT  64                 // wave-candidates per (batch, iter)
#define SLOTB  32                 // bytes per mail slot
#define RING   8                  // mailbox ring depth (skew<=1, 8 = margin)
#define FROUNDS 4                 // bounded sc0 poll rounds before sc1

typedef unsigned long long u64;
typedef unsigned int v4u __attribute__((ext_vector_type(4)));
typedef unsigned int v2u __attribute__((ext_vector_type(2)));

__device__ __forceinline__ u64 shfl_xor_u64(u64 v, int off) {
    unsigned lo = (unsigned)v, hi = (unsigned)(v >> 32);
    lo = __shfl_xor(lo, off, 64);
    hi = __shfl_xor(hi, off, 64);
    return ((u64)hi << 32) | lo;
}

// Message A (16B, one transaction): [w0=(it<<15)|(0x7FFF-idx), w1=distbits,
// w2=x, w3=y]; Message B (8B): [w0=A.w0, w1=z]. Valid iff A.x>>15 == it,
// B.x==A.x, distbits MSB==0. The embedded iteration tag rejects ring-stale
// slots (tag=it-RING), 0xAA poison (tag 0x15555 > 510), and zeros (tag 0
// only matches it=0, and ws is 0xAA-poisoned; prior-replay it=0 data is
// bit-identical -> benign, proven R7-R10 absmax 0.0). Tag bits sit ABOVE
// the idx bits, and all compared entries share a tag, so u64 key ordering
// (max dist, ties -> min idx) is unaffected. Tear impossible: each piece is
// a single naturally-aligned transaction, cross-checked via B.x==A.x.
__device__ __forceinline__ void mail_store(u64 addr, v4u A, v2u B) {
    // sc0 sc1: write through the XCD L2 (fast same-XCD readers) and to the
    // device coherence point (correct for any placement).
    asm volatile(
        "global_store_dwordx4 %0, %2, off sc0 sc1\n\t"
        "global_store_dwordx2 %1, %3, off sc0 sc1"
        :: "v"(addr), "v"(addr + 16), "v"(A), "v"(B) : "memory");
}
__device__ __forceinline__ void mail_loadF(u64 addr, v4u* A, v2u* B) {
    asm volatile(      // sc0: XCD-L2 visibility (fast path)
        "global_load_dwordx4 %0, %2, off sc0\n\t"
        "global_load_dwordx2 %1, %3, off sc0\n\t"
        "s_waitcnt vmcnt(0)"
        : "=v"(*A), "=v"(*B) : "v"(addr), "v"(addr + 16) : "memory");
}
__device__ __forceinline__ void mail_loadS(u64 addr, v4u* A, v2u* B) {
    asm volatile(      // sc0 sc1: device coherence point (always correct)
        "global_load_dwordx4 %0, %2, off sc0 sc1\n\t"
        "global_load_dwordx2 %1, %3, off sc0 sc1\n\t"
        "s_waitcnt vmcnt(0)"
        : "=v"(*A), "=v"(*B) : "v"(addr), "v"(addr + 16) : "memory");
}

// ---------------------------------------------------------------------------
// FPS: P=8 blocks/batch, points in LDS (48 KB, wave-owned), dist[8] VGPRs.
// R11: BARRIER-FREE exchange. R10's chain still held 2 barriers + redK +
// farbox LDS round-trips + a store gated behind barrier1 (~0.4us of
// orchestration). Now each WAVE posts its own candidate right after its
// shfl-reduce and polls all 64 wave-slots itself (one coalesced load pair
// per round, lane L <-> slot L), reducing 64 keys in-register. No
// __syncthreads in the loop at all; waves self-sync through the mailbox
// (skew provably <=1 iteration -> ring depth 8 safe with iteration tags).
// Traffic ~4x below R7's storm (coalesced, non-atomic).
// Distance math bit-exact vs reference: contract off, (dx^2+dy^2)+dz^2,
// fminf accumulate; key (distbits<<32 | tag|~idx15): max dist, ties -> min
// index; per-thread strict '>' in ascending order keeps first occurrence.
// ---------------------------------------------------------------------------
__global__ __launch_bounds__(THR) void fps_kernel(
    const float* __restrict__ xyz,
    const int* __restrict__ finit,
    int* __restrict__ cidx,        // [NBATCH][NFPS]
    u64 mailAddr)                  // mail[RING][NBATCH][NSLOT] slots of 32 B
{
#pragma clang fp contract(off)
    const int gb = blockIdx.x;
    const int b  = gb & 7;         // batch (gb%8 -> same XCD per batch)
    const int me = gb >> 3;        // sub-block within batch
    const int t  = threadIdx.x;
    const float* __restrict__ base = xyz + (size_t)b * (NPTS * 3);

    __shared__ float4 xs4[CHUNKS], ys4[CHUNKS], zs4[CHUNKS];   // 48 KB

    // ---- transpose own points into LDS; every LDS element is written and
    // read by the SAME thread -> no barrier needed anywhere ----
    float dist[4 * CPT];
#pragma unroll
    for (int j = 0; j < CPT; ++j) {
        const int c = t + j * THR;
        const float4* __restrict__ g4 =
            reinterpret_cast<const float4*>(base) + 3 * (me * CHUNKS + c);
        const float4 q0 = g4[0];
        const float4 q1 = g4[1];
        const float4 q2 = g4[2];
        xs4[c] = make_float4(q0.x, q0.w, q1.z, q2.y);
        ys4[c] = make_float4(q0.y, q1.x, q1.w, q2.z);
        zs4[c] = make_float4(q0.z, q1.y, q2.x, q2.w);
        dist[4 * j + 0] = BIGF; dist[4 * j + 1] = BIGF;
        dist[4 * j + 2] = BIGF; dist[4 * j + 3] = BIGF;
    }

    int far = finit[b];
    float cx = base[3 * far + 0];
    float cy = base[3 * far + 1];
    float cz = base[3 * far + 2];

    const int wid  = t >> 6;             // 0..7
    const int lane = t & 63;
    const int slotIdx = me * 8 + wid;    // this wave's slot in [0,64)

    for (int it = 0; it < NFPS; ++it) {
        if (me == 0 && t == 0) cidx[b * NFPS + it] = far;  // record BEFORE update
        if (it == NFPS - 1) break;                          // last far never used

        float vmax = -1.0f;
        int   amax = 0;

#define PROC(K, PX, PY, PZ, GI)                               \
        {                                                     \
            float dx = (PX) - cx;                             \
            float dy = (PY) - cy;                             \
            float dz = (PZ) - cz;                             \
            float d  = dx * dx + dy * dy;                     \
            d = d + dz * dz;                                  \
            float dk = fminf(dist[K], d);                     \
            dist[K] = dk;                                     \
            if (dk > vmax) { vmax = dk; amax = (GI); }        \
        }

#pragma unroll
        for (int j = 0; j < CPT; ++j) {
            const int c  = t + j * THR;
            const float4 xv = xs4[c];
            const float4 yv = ys4[c];
            const float4 zv = zs4[c];
            const int gi = me * PPB + 4 * c;
            PROC(4 * j + 0, xv.x, yv.x, zv.x, gi + 0);
            PROC(4 * j + 1, xv.y, yv.y, zv.y, gi + 1);
            PROC(4 * j + 2, xv.z, yv.z, zv.z, gi + 2);
            PROC(4 * j + 3, xv.w, yv.w, zv.w, gi + 3);
        }
#undef PROC

        // wave candidate: u64 key = distbits<<32 | (it<<15 | (0x7FFF-idx))
        const unsigned low = ((unsigned)it << 15)
                           | (unsigned)(0x7FFF - amax);
        u64 key = ((u64)__float_as_uint(vmax) << 32) | low;
#pragma unroll
        for (int off = 32; off >= 1; off >>= 1) {
            u64 o = shfl_xor_u64(key, off);
            key = (o > key) ? o : key;
        }

        const u64 rowAddr = mailAddr
            + (u64)(((it & (RING - 1)) * NBATCH + b) * NSLOT) * SLOTB;

        // post this wave's candidate (lane 0), immediately after the reduce
        if (lane == 0) {
            const int widx = 0x7FFF - (int)(key & 0x7FFF);   // global idx
            const int li   = widx - me * PPB;                // in [0, PPB)
            v4u A; v2u B;
            A.x = (unsigned)(key & 0xFFFFFFFFull);
            A.y = (unsigned)(key >> 32);
            A.z = __float_as_uint(reinterpret_cast<const float*>(xs4)[li]);
            A.w = __float_as_uint(reinterpret_cast<const float*>(ys4)[li]);
            B.x = A.x;
            B.y = __float_as_uint(reinterpret_cast<const float*>(zs4)[li]);
            mail_store(rowAddr + (u64)slotIdx * SLOTB, A, B);
        }

        // poll all 64 wave-slots: lane L owns slot L (fully coalesced)
        const u64 myAddr = rowAddr + (u64)lane * SLOTB;
        v4u A; v2u B;
        bool have = false;
        int  fr = FROUNDS;
        for (;;) {
            if (!have) {
                if (fr > 0) mail_loadF(myAddr, &A, &B);
                else        mail_loadS(myAddr, &A, &B);
                have = ((A.x >> 15) == (unsigned)it)
                     && (B.x == A.x)
                     && ((A.y >> 31) == 0);
            }
            --fr;
            if (__all(have ? 1 : 0)) break;
        }

        // 64-lane reduce carrying winner coords
        u64   k  = ((u64)A.y << 32) | A.x;
        float px = __uint_as_float(A.z);
        float py = __uint_as_float(A.w);
        float pz = __uint_as_float(B.y);
#pragma unroll
        for (int off = 32; off >= 1; off >>= 1) {
            const u64   ok = shfl_xor_u64(k, off);
            const float ox = __shfl_xor(px, off, 64);
            const float oy = __shfl_xor(py, off, 64);
            const float oz = __shfl_xor(pz, off, 64);
            if (ok > k) { k = ok; px = ox; py = oy; pz = oz; }
        }
        far = 0x7FFF - (int)(k & 0x7FFF);
        cx = px; cy = py; cz = pz;
    }
}

// ---------------------------------------------------------------------------
// Ball query + grouping: QPB centroids per block (unchanged from R8-R10).
// ---------------------------------------------------------------------------
__global__ __launch_bounds__(256) void ballq_kernel(
    const float* __restrict__ xyz,
    const int* __restrict__ cidx,
    float* __restrict__ out0,      // [B][S][33][3]
    float* __restrict__ out1)      // [B][S][3]
{
#pragma clang fp contract(off)
    const int blk0 = blockIdx.x * QPB;   // first global centroid (b*NFPS+s)
    const int b    = blk0 >> 9;          // QPB divides NFPS -> same batch
    const int t    = threadIdx.x;
    const float* __restrict__ base = xyz + (size_t)b * (NPTS * 3);

    __shared__ u64 list[QPB][CAP];
    __shared__ int scnt[QPB];
    __shared__ u64 mask0[QPB];
    __shared__ int selIdx[QPB][NGRP];

    if (t < QPB) scnt[t] = 0;

    float cxs[QPB], cys[QPB], czs[QPB];
#pragma unroll
    for (int q = 0; q < QPB; ++q) {
        const int ci = cidx[blk0 + q];
        cxs[q] = base[3 * ci + 0];
        cys[q] = base[3 * ci + 1];
        czs[q] = base[3 * ci + 2];
    }
    __syncthreads();

    // in-ball masks for the first 64 indices (fill candidates); wave 0 only
    if (t < 64) {
        const float px = base[3 * t + 0];
        const float py = base[3 * t + 1];
        const float pz = base[3 * t + 2];
#pragma unroll
        for (int q = 0; q < QPB; ++q) {
            float dx = px - cxs[q];
            float dy = py - cys[q];
            float dz = pz - czs[q];
            float d  = dx * dx + dy * dy;
            d = d + dz * dz;
            u64 mk = __ballot(d <= R2F);
            if (t == 0) mask0[q] = mk;
        }
    }

    // scan all points once; test against all QPB centroids
    for (int k = 0; k < NPTS / 256; ++k) {
        const int p = k * 256 + t;
        const float px = base[3 * p + 0];
        const float py = base[3 * p + 1];
        const float pz = base[3 * p + 2];
#pragma unroll
        for (int q = 0; q < QPB; ++q) {
            float dx = px - cxs[q];
            float dy = py - cys[q];
            float dz = pz - czs[q];
            float d  = dx * dx + dy * dy;
            d = d + dz * dz;
            if (d <= R2F) {
                int pos = atomicAdd(&scnt[q], 1);
                if (pos < CAP)
                    list[q][pos] = (((u64)__float_as_uint(d)) << 32)
                                   | (unsigned)p;
            }
        }
    }
    __syncthreads();

    // rank-based selection, one wave per centroid:
    // key's rank == #smaller keys (keys unique via idx)
    {
        const int q    = t >> 6;     // wave id 0..3
        const int lane = t & 63;
        const int m = min(scnt[q], CAP);
        for (int j = lane; j < m; j += 64) {
            const u64 kj = list[q][j];
            int rank = 0;
            for (int i = 0; i < m; ++i) rank += (list[q][i] < kj) ? 1 : 0;
            if (rank < NGRP) selIdx[q][rank] = (int)(kj & 0xffffffffu);
        }
    }
    __syncthreads();

    if (t < 33 * QPB) {
        const int q    = t / 33;
        const int slot = t % 33;
        const int sg   = blk0 + q;
        const float cx = cxs[q], cy = cys[q], cz = czs[q];
        const size_t o0 = (size_t)sg * 33 * 3;
        if (slot == 32) {
            out0[o0 + 0] = cx; out0[o0 + 1] = cy; out0[o0 + 2] = cz;
            const size_t o1 = (size_t)sg * 3;
            out1[o1 + 0] = cx; out1[o1 + 1] = cy; out1[o1 + 2] = cz;
        } else {
            const int m = min(scnt[q], CAP);
            const int K = min(m, NGRP);
            int idx;
            if (slot < K) {
                idx = selIdx[q][slot];
            } else {
                // (slot-K+1)-th zero bit of mask0 = next out-of-radius index
                u64 zeros = ~mask0[q];
                const int need = slot - K;
                for (int z = 0; z < need; ++z) zeros &= zeros - 1;
                idx = __builtin_ctzll(zeros);
            }
            const float px = base[3 * idx + 0];
            const float py = base[3 * idx + 1];
            const float pz = base[3 * idx + 2];
            out0[o0 + (size_t)(1 + slot) * 3 + 0] = px - cx;
            out0[o0 + (size_t)(1 + slot) * 3 + 1] = py - cy;
            out0[o0 + (size_t)(1 + slot) * 3 + 2] = pz - cz;
        }
    }
}

extern "C" void kernel_launch(void* const* d_in, const int* in_sizes, int n_in,
                              void* d_out, int out_size, void* d_ws, size_t ws_size,
                              hipStream_t stream) {
    const float* xyz   = (const float*)d_in[0];
    const int*   finit = (const int*)d_in[1];
    float* out0 = (float*)d_out;
    float* out1 = out0 + (size_t)NBATCH * NFPS * 33 * 3;

    // ws layout: cidx 16 KB | mail RING*NBATCH*NSLOT*32 B = 128 KB
    // total 144 KB << 1.06 MB proven available in R1-R3.
    int* cidx = (int*)d_ws;
    u64  mailAddr = (u64)(uintptr_t)((char*)d_ws
                   + (size_t)NBATCH * NFPS * sizeof(int));

    fps_kernel<<<NBATCH * P, THR, 0, stream>>>(xyz, finit, cidx, mailAddr);
    ballq_kernel<<<(NBATCH * NFPS) / QPB, 256, 0, stream>>>(xyz, cidx, out0, out1);
}